// Round 1
// baseline (74.918 us; speedup 1.0000x reference)
//
#include <hip/hip_runtime.h>
#include <math.h>

#define DEG 16
#define FDIM 128
#define EPSV 1e-12f

// Kernel 1: per-node inverse L2 norm -> ws
__global__ void agnn_rnorm_kernel(const float* __restrict__ x,
                                  float* __restrict__ rn, int n) {
    int wave = (blockIdx.x * blockDim.x + threadIdx.x) >> 6;
    int lane = threadIdx.x & 63;
    if (wave >= n) return;
    const float2 v = *reinterpret_cast<const float2*>(x + (size_t)wave * FDIM + lane * 2);
    float s = v.x * v.x + v.y * v.y;
#pragma unroll
    for (int off = 32; off >= 1; off >>= 1)
        s += __shfl_xor(s, off);
    if (lane == 0) rn[wave] = rsqrtf(s + EPSV);
}

// Kernel 2: one wave per node. Gather 16 neighbor rows once (kept in regs),
// joint butterfly reduce for the 16 dots, softmax, weighted aggregate.
__global__ void agnn_main_kernel(const float* __restrict__ x,
                                 const int* __restrict__ col_id,
                                 const float* __restrict__ rn,
                                 const float* __restrict__ beta,
                                 float* __restrict__ out, int n) {
    int wave = (blockIdx.x * blockDim.x + threadIdx.x) >> 6;
    int lane = threadIdx.x & 63;
    if (wave >= n) return;
    const int node = wave;

    const float b   = beta[0];
    const float rni = rn[node];
    const float2 xi = *reinterpret_cast<const float2*>(x + (size_t)node * FDIM + lane * 2);

    // lane l holds neighbor index (l & 15); broadcast via shfl
    int cidx = col_id[node * DEG + (lane & 15)];

    float2 xj[DEG];
    float  p[DEG];
    float  rnj[DEG];
#pragma unroll
    for (int k = 0; k < DEG; ++k) {
        int cj = __shfl(cidx, k);                 // uniform across wave
        const float2 v = *reinterpret_cast<const float2*>(x + (size_t)cj * FDIM + lane * 2);
        xj[k]  = v;
        rnj[k] = rn[cj];
        p[k]   = xi.x * v.x + xi.y * v.y;
    }

    // joint butterfly reduction: after this, every lane has all 16 full dots
#pragma unroll
    for (int off = 32; off >= 1; off >>= 1) {
#pragma unroll
        for (int k = 0; k < DEG; ++k)
            p[k] += __shfl_xor(p[k], off);
    }

    const float brni = b * rni;
#pragma unroll
    for (int k = 0; k < DEG; ++k)
        p[k] *= brni * rnj[k];

    // softmax over the 16 neighbors (redundant in every lane)
    float m = p[0];
#pragma unroll
    for (int k = 1; k < DEG; ++k) m = fmaxf(m, p[k]);
    float s = 0.f;
#pragma unroll
    for (int k = 0; k < DEG; ++k) { p[k] = __expf(p[k] - m); s += p[k]; }
    const float inv = 1.0f / s;

    float2 acc = make_float2(0.f, 0.f);
#pragma unroll
    for (int k = 0; k < DEG; ++k) {
        const float a = p[k] * inv;
        acc.x = fmaf(a, xj[k].x, acc.x);
        acc.y = fmaf(a, xj[k].y, acc.y);
    }
    *reinterpret_cast<float2*>(out + (size_t)node * FDIM + lane * 2) = acc;
}

extern "C" void kernel_launch(void* const* d_in, const int* in_sizes, int n_in,
                              void* d_out, int out_size, void* d_ws, size_t ws_size,
                              hipStream_t stream) {
    const float* x      = (const float*)d_in[0];
    // d_in[1] = row_id (unused: fixed degree), d_in[2] = row_ptr (unused)
    const int*   col_id = (const int*)d_in[3];
    const float* beta   = (const float*)d_in[4];
    float*       out    = (float*)d_out;
    float*       rn     = (float*)d_ws;          // N floats of scratch

    const int n = in_sizes[0] / FDIM;            // 50000

    const int block = 256;                       // 4 waves / block
    const int wavesPerBlock = block / 64;
    const int grid = (n + wavesPerBlock - 1) / wavesPerBlock;

    agnn_rnorm_kernel<<<grid, block, 0, stream>>>(x, rn, n);
    agnn_main_kernel<<<grid, block, 0, stream>>>(x, col_id, rn, beta, out, n);
}

// Round 2
// 74.197 us; speedup vs baseline: 1.0097x; 1.0097x over previous
//
#include <hip/hip_runtime.h>
#include <math.h>
#include <stdint.h>

#define DEG 16
#define FDIM 128
#define EPSV 1e-12f

__device__ __forceinline__ uint32_t f32_to_bf16_rne(float f) {
    uint32_t u = __float_as_uint(f);
    return (u + 0x7fffu + ((u >> 16) & 1u)) >> 16;
}

__device__ __forceinline__ float2 bf2_to_f2(uint32_t u) {
    float2 r;
    r.x = __uint_as_float(u << 16);
    r.y = __uint_as_float(u & 0xffff0000u);
    return r;
}

// Prep: one wave per row. Computes rsqrt(|x|^2+eps) from fp32 AND writes a
// packed-bf16 (RNE) copy of x into ws. One streaming pass over x.
__global__ void agnn_prep_kernel(const float* __restrict__ x,
                                 uint32_t* __restrict__ xbf,
                                 float* __restrict__ rn, int n) {
    int wave = (blockIdx.x * blockDim.x + threadIdx.x) >> 6;
    int lane = threadIdx.x & 63;
    if (wave >= n) return;
    const float2 v = *reinterpret_cast<const float2*>(x + (size_t)wave * FDIM + lane * 2);
    float s = v.x * v.x + v.y * v.y;
#pragma unroll
    for (int off = 32; off >= 1; off >>= 1)
        s += __shfl_xor(s, off);
    if (lane == 0) rn[wave] = rsqrtf(s + EPSV);
    xbf[(size_t)wave * (FDIM / 2) + lane] =
        f32_to_bf16_rne(v.x) | (f32_to_bf16_rne(v.y) << 16);
}

// Main (bf16 gather): one wave per node. 16 neighbor rows gathered once as
// packed bf16 (256B/row), kept in registers as float2; joint butterfly for
// the 16 dots; softmax; fp32-accumulated aggregation; fp32 output.
__global__ void agnn_main_bf16(const uint32_t* __restrict__ xbf,
                               const int* __restrict__ col_id,
                               const float* __restrict__ rn,
                               const float* __restrict__ beta,
                               float* __restrict__ out, int n) {
    int wave = (blockIdx.x * blockDim.x + threadIdx.x) >> 6;
    int lane = threadIdx.x & 63;
    if (wave >= n) return;
    const int node = wave;

    const float b   = beta[0];
    const float rni = rn[node];
    const float2 xi = bf2_to_f2(xbf[(size_t)node * (FDIM / 2) + lane]);

    int cidx = col_id[node * DEG + (lane & 15)];

    float2 xj[DEG];
    float  p[DEG];
    float  rnj[DEG];
#pragma unroll
    for (int k = 0; k < DEG; ++k) {
        int cj = __shfl(cidx, k);
        const uint32_t u = xbf[(size_t)cj * (FDIM / 2) + lane];
        const float2 v = bf2_to_f2(u);
        xj[k]  = v;
        rnj[k] = rn[cj];
        p[k]   = fmaf(xi.x, v.x, xi.y * v.y);
    }

    // joint butterfly: every lane ends with all 16 full dots
#pragma unroll
    for (int off = 32; off >= 1; off >>= 1) {
#pragma unroll
        for (int k = 0; k < DEG; ++k)
            p[k] += __shfl_xor(p[k], off);
    }

    const float brni = b * rni;
#pragma unroll
    for (int k = 0; k < DEG; ++k)
        p[k] *= brni * rnj[k];

    float m = p[0];
#pragma unroll
    for (int k = 1; k < DEG; ++k) m = fmaxf(m, p[k]);
    float s = 0.f;
#pragma unroll
    for (int k = 0; k < DEG; ++k) { p[k] = __expf(p[k] - m); s += p[k]; }
    const float inv = 1.0f / s;

    float2 acc = make_float2(0.f, 0.f);
#pragma unroll
    for (int k = 0; k < DEG; ++k) {
        const float a = p[k] * inv;
        acc.x = fmaf(a, xj[k].x, acc.x);
        acc.y = fmaf(a, xj[k].y, acc.y);
    }
    *reinterpret_cast<float2*>(out + (size_t)node * FDIM + lane * 2) = acc;
}

// ---------- fp32 fallback (used only if ws is too small for the bf16 copy) --
__global__ void agnn_rnorm_kernel(const float* __restrict__ x,
                                  float* __restrict__ rn, int n) {
    int wave = (blockIdx.x * blockDim.x + threadIdx.x) >> 6;
    int lane = threadIdx.x & 63;
    if (wave >= n) return;
    const float2 v = *reinterpret_cast<const float2*>(x + (size_t)wave * FDIM + lane * 2);
    float s = v.x * v.x + v.y * v.y;
#pragma unroll
    for (int off = 32; off >= 1; off >>= 1)
        s += __shfl_xor(s, off);
    if (lane == 0) rn[wave] = rsqrtf(s + EPSV);
}

__global__ void agnn_main_f32(const float* __restrict__ x,
                              const int* __restrict__ col_id,
                              const float* __restrict__ rn,
                              const float* __restrict__ beta,
                              float* __restrict__ out, int n) {
    int wave = (blockIdx.x * blockDim.x + threadIdx.x) >> 6;
    int lane = threadIdx.x & 63;
    if (wave >= n) return;
    const int node = wave;
    const float b   = beta[0];
    const float rni = rn[node];
    const float2 xi = *reinterpret_cast<const float2*>(x + (size_t)node * FDIM + lane * 2);
    int cidx = col_id[node * DEG + (lane & 15)];
    float2 xj[DEG];
    float  p[DEG];
    float  rnj[DEG];
#pragma unroll
    for (int k = 0; k < DEG; ++k) {
        int cj = __shfl(cidx, k);
        const float2 v = *reinterpret_cast<const float2*>(x + (size_t)cj * FDIM + lane * 2);
        xj[k] = v; rnj[k] = rn[cj];
        p[k] = fmaf(xi.x, v.x, xi.y * v.y);
    }
#pragma unroll
    for (int off = 32; off >= 1; off >>= 1) {
#pragma unroll
        for (int k = 0; k < DEG; ++k)
            p[k] += __shfl_xor(p[k], off);
    }
    const float brni = b * rni;
#pragma unroll
    for (int k = 0; k < DEG; ++k) p[k] *= brni * rnj[k];
    float m = p[0];
#pragma unroll
    for (int k = 1; k < DEG; ++k) m = fmaxf(m, p[k]);
    float s = 0.f;
#pragma unroll
    for (int k = 0; k < DEG; ++k) { p[k] = __expf(p[k] - m); s += p[k]; }
    const float inv = 1.0f / s;
    float2 acc = make_float2(0.f, 0.f);
#pragma unroll
    for (int k = 0; k < DEG; ++k) {
        const float a = p[k] * inv;
        acc.x = fmaf(a, xj[k].x, acc.x);
        acc.y = fmaf(a, xj[k].y, acc.y);
    }
    *reinterpret_cast<float2*>(out + (size_t)node * FDIM + lane * 2) = acc;
}

extern "C" void kernel_launch(void* const* d_in, const int* in_sizes, int n_in,
                              void* d_out, int out_size, void* d_ws, size_t ws_size,
                              hipStream_t stream) {
    const float* x      = (const float*)d_in[0];
    const int*   col_id = (const int*)d_in[3];
    const float* beta   = (const float*)d_in[4];
    float*       out    = (float*)d_out;

    const int n = in_sizes[0] / FDIM;            // 50000

    const int block = 256;                       // 4 waves / block
    const int wavesPerBlock = block / 64;
    const int grid = (n + wavesPerBlock - 1) / wavesPerBlock;

    const size_t xbf_bytes = (size_t)n * (FDIM / 2) * sizeof(uint32_t);  // 12.8 MB
    const size_t need = xbf_bytes + (size_t)n * sizeof(float);

    if (ws_size >= need) {
        uint32_t* xbf = (uint32_t*)d_ws;
        float*    rn  = (float*)((char*)d_ws + xbf_bytes);
        agnn_prep_kernel<<<grid, block, 0, stream>>>(x, xbf, rn, n);
        agnn_main_bf16<<<grid, block, 0, stream>>>(xbf, col_id, rn, beta, out, n);
    } else {
        float* rn = (float*)d_ws;                // N floats
        agnn_rnorm_kernel<<<grid, block, 0, stream>>>(x, rn, n);
        agnn_main_f32<<<grid, block, 0, stream>>>(x, col_id, rn, beta, out, n);
    }
}

// Round 3
// 44.038 us; speedup vs baseline: 1.7012x; 1.6849x over previous
//
#include <hip/hip_runtime.h>
#include <math.h>
#include <stdint.h>

#define DEG 16
#define FDIM 128
#define EPSV 1e-12f

__device__ __forceinline__ uint32_t f32_to_bf16_rne(float f) {
    uint32_t u = __float_as_uint(f);
    return (u + 0x7fffu + ((u >> 16) & 1u)) >> 16;
}

__device__ __forceinline__ void unpack8(const uint4 u, float* f) {
    f[0] = __uint_as_float(u.x << 16); f[1] = __uint_as_float(u.x & 0xffff0000u);
    f[2] = __uint_as_float(u.y << 16); f[3] = __uint_as_float(u.y & 0xffff0000u);
    f[4] = __uint_as_float(u.z << 16); f[5] = __uint_as_float(u.z & 0xffff0000u);
    f[6] = __uint_as_float(u.w << 16); f[7] = __uint_as_float(u.w & 0xffff0000u);
}

// Prep: one wave per row. rsqrt(|x|^2+eps) from fp32 AND packed-bf16 copy.
__global__ void agnn_prep_kernel(const float* __restrict__ x,
                                 uint32_t* __restrict__ xbf,
                                 float* __restrict__ rn, int n) {
    int wave = (blockIdx.x * blockDim.x + threadIdx.x) >> 6;
    int lane = threadIdx.x & 63;
    if (wave >= n) return;
    const float2 v = *reinterpret_cast<const float2*>(x + (size_t)wave * FDIM + lane * 2);
    float s = v.x * v.x + v.y * v.y;
#pragma unroll
    for (int off = 32; off >= 1; off >>= 1)
        s += __shfl_xor(s, off);
    if (lane == 0) rn[wave] = rsqrtf(s + EPSV);
    xbf[(size_t)wave * (FDIM / 2) + lane] =
        f32_to_bf16_rne(v.x) | (f32_to_bf16_rne(v.y) << 16);
}

// Main v3: one wave per node, 4 groups x 16 lanes. Group g owns neighbors
// 4g..4g+3; lane t owns feature chunk [8t, 8t+8) (one dwordx4 of packed bf16).
// 4x fewer gather instructions, 4-step intra-group reduce + 2 cross-group.
__global__ void agnn_main_v3(const uint32_t* __restrict__ xbf,
                             const int* __restrict__ col_id,
                             const float* __restrict__ rn,
                             const float* __restrict__ beta,
                             float* __restrict__ out, int n) {
    int wave = (blockIdx.x * blockDim.x + threadIdx.x) >> 6;
    int lane = threadIdx.x & 63;
    if (wave >= n) return;
    const int node = wave;
    const int g = lane >> 4;       // group 0..3
    const int t = lane & 15;       // chunk index within row

    const float b   = beta[0];
    const float rni = rn[node];

    const uint4 xiu = *reinterpret_cast<const uint4*>(xbf + (size_t)node * (FDIM / 2) + t * 4);
    float xi[8];
    unpack8(xiu, xi);

    const int call = col_id[node * DEG + t];   // lane t holds neighbor t's col

    // gather: group g loads rows of neighbors 4g+r, r=0..3 (16B/lane)
    int   cj[4];
    uint4 xju[4];
#pragma unroll
    for (int r = 0; r < 4; ++r) {
        cj[r]  = __shfl(call, 4 * g + r);
        xju[r] = *reinterpret_cast<const uint4*>(xbf + (size_t)cj[r] * (FDIM / 2) + t * 4);
    }
    float rnj[4];
#pragma unroll
    for (int r = 0; r < 4; ++r) rnj[r] = rn[cj[r]];

    // per-lane partial dots (8 elems each)
    float p[4];
#pragma unroll
    for (int r = 0; r < 4; ++r) {
        float xv[8];
        unpack8(xju[r], xv);
        float d0 = xi[0] * xv[0];
        float d1 = xi[1] * xv[1];
#pragma unroll
        for (int q = 2; q < 8; q += 2) {
            d0 = fmaf(xi[q],     xv[q],     d0);
            d1 = fmaf(xi[q + 1], xv[q + 1], d1);
        }
        p[r] = d0 + d1;
    }

    // intra-group (16-lane) joint butterfly: 4 steps x 4 values
#pragma unroll
    for (int off = 1; off < 16; off <<= 1) {
#pragma unroll
        for (int r = 0; r < 4; ++r)
            p[r] += __shfl_xor(p[r], off);
    }

    const float brni = b * rni;
#pragma unroll
    for (int r = 0; r < 4; ++r)
        p[r] *= brni * rnj[r];

    // softmax across all 16 neighbors: local max/sum + 2 cross-group steps
    float m = fmaxf(fmaxf(p[0], p[1]), fmaxf(p[2], p[3]));
    m = fmaxf(m, __shfl_xor(m, 16));
    m = fmaxf(m, __shfl_xor(m, 32));
    float s = 0.f;
#pragma unroll
    for (int r = 0; r < 4; ++r) { p[r] = __expf(p[r] - m); s += p[r]; }
    s += __shfl_xor(s, 16);
    s += __shfl_xor(s, 32);
    const float inv = 1.0f / s;

    // aggregation: group-local weighted sum, then cross-group reduce
    float acc[8] = {0.f, 0.f, 0.f, 0.f, 0.f, 0.f, 0.f, 0.f};
#pragma unroll
    for (int r = 0; r < 4; ++r) {
        const float a = p[r] * inv;
        float xv[8];
        unpack8(xju[r], xv);
#pragma unroll
        for (int q = 0; q < 8; ++q)
            acc[q] = fmaf(a, xv[q], acc[q]);
    }
#pragma unroll
    for (int q = 0; q < 8; ++q) acc[q] += __shfl_xor(acc[q], 16);
#pragma unroll
    for (int q = 0; q < 8; ++q) acc[q] += __shfl_xor(acc[q], 32);

    if (g == 0) {
        float4* op = reinterpret_cast<float4*>(out + (size_t)node * FDIM + t * 8);
        op[0] = make_float4(acc[0], acc[1], acc[2], acc[3]);
        op[1] = make_float4(acc[4], acc[5], acc[6], acc[7]);
    }
}

// ---------- fp32 fallback (only if ws too small for the bf16 copy) ----------
__global__ void agnn_rnorm_kernel(const float* __restrict__ x,
                                  float* __restrict__ rn, int n) {
    int wave = (blockIdx.x * blockDim.x + threadIdx.x) >> 6;
    int lane = threadIdx.x & 63;
    if (wave >= n) return;
    const float2 v = *reinterpret_cast<const float2*>(x + (size_t)wave * FDIM + lane * 2);
    float s = v.x * v.x + v.y * v.y;
#pragma unroll
    for (int off = 32; off >= 1; off >>= 1)
        s += __shfl_xor(s, off);
    if (lane == 0) rn[wave] = rsqrtf(s + EPSV);
}

__global__ void agnn_main_f32(const float* __restrict__ x,
                              const int* __restrict__ col_id,
                              const float* __restrict__ rn,
                              const float* __restrict__ beta,
                              float* __restrict__ out, int n) {
    int wave = (blockIdx.x * blockDim.x + threadIdx.x) >> 6;
    int lane = threadIdx.x & 63;
    if (wave >= n) return;
    const int node = wave;
    const float b   = beta[0];
    const float rni = rn[node];
    const float2 xi = *reinterpret_cast<const float2*>(x + (size_t)node * FDIM + lane * 2);
    int cidx = col_id[node * DEG + (lane & 15)];
    float2 xj[DEG];
    float  p[DEG];
    float  rnj[DEG];
#pragma unroll
    for (int k = 0; k < DEG; ++k) {
        int cj = __shfl(cidx, k);
        const float2 v = *reinterpret_cast<const float2*>(x + (size_t)cj * FDIM + lane * 2);
        xj[k] = v; rnj[k] = rn[cj];
        p[k] = fmaf(xi.x, v.x, xi.y * v.y);
    }
#pragma unroll
    for (int off = 32; off >= 1; off >>= 1) {
#pragma unroll
        for (int k = 0; k < DEG; ++k)
            p[k] += __shfl_xor(p[k], off);
    }
    const float brni = b * rni;
#pragma unroll
    for (int k = 0; k < DEG; ++k) p[k] *= brni * rnj[k];
    float m = p[0];
#pragma unroll
    for (int k = 1; k < DEG; ++k) m = fmaxf(m, p[k]);
    float s = 0.f;
#pragma unroll
    for (int k = 0; k < DEG; ++k) { p[k] = __expf(p[k] - m); s += p[k]; }
    const float inv = 1.0f / s;
    float2 acc = make_float2(0.f, 0.f);
#pragma unroll
    for (int k = 0; k < DEG; ++k) {
        const float a = p[k] * inv;
        acc.x = fmaf(a, xj[k].x, acc.x);
        acc.y = fmaf(a, xj[k].y, acc.y);
    }
    *reinterpret_cast<float2*>(out + (size_t)node * FDIM + lane * 2) = acc;
}

extern "C" void kernel_launch(void* const* d_in, const int* in_sizes, int n_in,
                              void* d_out, int out_size, void* d_ws, size_t ws_size,
                              hipStream_t stream) {
    const float* x      = (const float*)d_in[0];
    const int*   col_id = (const int*)d_in[3];
    const float* beta   = (const float*)d_in[4];
    float*       out    = (float*)d_out;

    const int n = in_sizes[0] / FDIM;            // 50000

    const int block = 256;                       // 4 waves / block
    const int wavesPerBlock = block / 64;
    const int grid = (n + wavesPerBlock - 1) / wavesPerBlock;

    const size_t xbf_bytes = (size_t)n * (FDIM / 2) * sizeof(uint32_t);  // 12.8 MB
    const size_t need = xbf_bytes + (size_t)n * sizeof(float);

    if (ws_size >= need) {
        uint32_t* xbf = (uint32_t*)d_ws;
        float*    rn  = (float*)((char*)d_ws + xbf_bytes);
        agnn_prep_kernel<<<grid, block, 0, stream>>>(x, xbf, rn, n);
        agnn_main_v3<<<grid, block, 0, stream>>>(xbf, col_id, rn, beta, out, n);
    } else {
        float* rn = (float*)d_ws;
        agnn_rnorm_kernel<<<grid, block, 0, stream>>>(x, rn, n);
        agnn_main_f32<<<grid, block, 0, stream>>>(x, col_id, rn, beta, out, n);
    }
}

// Round 4
// 42.994 us; speedup vs baseline: 1.7425x; 1.0243x over previous
//
#include <hip/hip_runtime.h>
#include <math.h>
#include <stdint.h>

#define DEG 16
#define FDIM 128
#define EPSV 1e-12f

__device__ __forceinline__ uint32_t f32_to_bf16_rne(float f) {
    uint32_t u = __float_as_uint(f);
    return (u + 0x7fffu + ((u >> 16) & 1u)) >> 16;
}

__device__ __forceinline__ void unpack8(const uint4 u, float* f) {
    f[0] = __uint_as_float(u.x << 16); f[1] = __uint_as_float(u.x & 0xffff0000u);
    f[2] = __uint_as_float(u.y << 16); f[3] = __uint_as_float(u.y & 0xffff0000u);
    f[4] = __uint_as_float(u.z << 16); f[5] = __uint_as_float(u.z & 0xffff0000u);
    f[6] = __uint_as_float(u.w << 16); f[7] = __uint_as_float(u.w & 0xffff0000u);
}

// Prep: one wave per row. rsqrt(|x|^2+eps) from fp32 AND packed-bf16 copy.
__global__ void agnn_prep_kernel(const float* __restrict__ x,
                                 uint32_t* __restrict__ xbf,
                                 float* __restrict__ rn, int n) {
    int wave = (blockIdx.x * blockDim.x + threadIdx.x) >> 6;
    int lane = threadIdx.x & 63;
    if (wave >= n) return;
    const float2 v = *reinterpret_cast<const float2*>(x + (size_t)wave * FDIM + lane * 2);
    float s = v.x * v.x + v.y * v.y;
#pragma unroll
    for (int off = 32; off >= 1; off >>= 1)
        s += __shfl_xor(s, off);
    if (lane == 0) rn[wave] = rsqrtf(s + EPSV);
    xbf[(size_t)wave * (FDIM / 2) + lane] =
        f32_to_bf16_rne(v.x) | (f32_to_bf16_rne(v.y) << 16);
}

// Main v4: one wave per node, 4 groups x 16 lanes. Group g owns neighbors
// 4g..4g+3; lane t owns feature chunk [8t,8t+8). Changes vs v3:
//  - neighbor ids via one uniform int4 load (no col->shfl dependency round)
//  - neighbors unpacked ONCE, floats kept in registers for dot + aggregate
//  - all memory issued up front for max loads-in-flight
__global__ void agnn_main_v4(const uint32_t* __restrict__ xbf,
                             const int* __restrict__ col_id,
                             const float* __restrict__ rn,
                             const float* __restrict__ beta,
                             float* __restrict__ out, int n) {
    int wave = (blockIdx.x * blockDim.x + threadIdx.x) >> 6;
    int lane = threadIdx.x & 63;
    if (wave >= n) return;
    const int node = wave;
    const int g = lane >> 4;       // group 0..3 -> neighbors 4g..4g+3
    const int t = lane & 15;       // 16B chunk index within row

    // ---- issue independent loads first ----
    const int4  c4  = *reinterpret_cast<const int4*>(col_id + node * DEG + 4 * g); // uniform in group
    const uint4 xiu = *reinterpret_cast<const uint4*>(xbf + (size_t)node * (FDIM / 2) + t * 4);
    const float b   = beta[0];
    const float rni = rn[node];

    // gathers: 4 independent 16B loads + 4 scalar-ish rn loads
    uint4 xju0 = *reinterpret_cast<const uint4*>(xbf + (size_t)c4.x * (FDIM / 2) + t * 4);
    uint4 xju1 = *reinterpret_cast<const uint4*>(xbf + (size_t)c4.y * (FDIM / 2) + t * 4);
    uint4 xju2 = *reinterpret_cast<const uint4*>(xbf + (size_t)c4.z * (FDIM / 2) + t * 4);
    uint4 xju3 = *reinterpret_cast<const uint4*>(xbf + (size_t)c4.w * (FDIM / 2) + t * 4);
    float rnj0 = rn[c4.x], rnj1 = rn[c4.y], rnj2 = rn[c4.z], rnj3 = rn[c4.w];

    float xi[8];
    unpack8(xiu, xi);

    // unpack neighbors once; keep in registers
    float xv0[8], xv1[8], xv2[8], xv3[8];
    unpack8(xju0, xv0);
    unpack8(xju1, xv1);
    unpack8(xju2, xv2);
    unpack8(xju3, xv3);

    // per-lane partial dots
    float p[4];
    {
        float d0, d1;
        d0 = xi[0] * xv0[0]; d1 = xi[1] * xv0[1];
#pragma unroll
        for (int q = 2; q < 8; q += 2) { d0 = fmaf(xi[q], xv0[q], d0); d1 = fmaf(xi[q+1], xv0[q+1], d1); }
        p[0] = d0 + d1;
        d0 = xi[0] * xv1[0]; d1 = xi[1] * xv1[1];
#pragma unroll
        for (int q = 2; q < 8; q += 2) { d0 = fmaf(xi[q], xv1[q], d0); d1 = fmaf(xi[q+1], xv1[q+1], d1); }
        p[1] = d0 + d1;
        d0 = xi[0] * xv2[0]; d1 = xi[1] * xv2[1];
#pragma unroll
        for (int q = 2; q < 8; q += 2) { d0 = fmaf(xi[q], xv2[q], d0); d1 = fmaf(xi[q+1], xv2[q+1], d1); }
        p[2] = d0 + d1;
        d0 = xi[0] * xv3[0]; d1 = xi[1] * xv3[1];
#pragma unroll
        for (int q = 2; q < 8; q += 2) { d0 = fmaf(xi[q], xv3[q], d0); d1 = fmaf(xi[q+1], xv3[q+1], d1); }
        p[3] = d0 + d1;
    }

    // intra-group (16-lane) joint butterfly: 4 steps x 4 values
#pragma unroll
    for (int off = 1; off < 16; off <<= 1) {
#pragma unroll
        for (int r = 0; r < 4; ++r)
            p[r] += __shfl_xor(p[r], off);
    }

    const float brni = b * rni;
    p[0] *= brni * rnj0;
    p[1] *= brni * rnj1;
    p[2] *= brni * rnj2;
    p[3] *= brni * rnj3;

    // softmax across 16 neighbors: local + 2 cross-group steps
    float m = fmaxf(fmaxf(p[0], p[1]), fmaxf(p[2], p[3]));
    m = fmaxf(m, __shfl_xor(m, 16));
    m = fmaxf(m, __shfl_xor(m, 32));
    float s = 0.f;
#pragma unroll
    for (int r = 0; r < 4; ++r) { p[r] = __expf(p[r] - m); s += p[r]; }
    s += __shfl_xor(s, 16);
    s += __shfl_xor(s, 32);
    const float inv = 1.0f / s;

    // aggregation from the register-resident unpacked rows
    const float a0 = p[0] * inv, a1 = p[1] * inv, a2 = p[2] * inv, a3 = p[3] * inv;
    float acc[8];
#pragma unroll
    for (int q = 0; q < 8; ++q) {
        float v = a0 * xv0[q];
        v = fmaf(a1, xv1[q], v);
        v = fmaf(a2, xv2[q], v);
        v = fmaf(a3, xv3[q], v);
        acc[q] = v;
    }
#pragma unroll
    for (int q = 0; q < 8; ++q) acc[q] += __shfl_xor(acc[q], 16);
#pragma unroll
    for (int q = 0; q < 8; ++q) acc[q] += __shfl_xor(acc[q], 32);

    if (g == 0) {
        float4* op = reinterpret_cast<float4*>(out + (size_t)node * FDIM + t * 8);
        op[0] = make_float4(acc[0], acc[1], acc[2], acc[3]);
        op[1] = make_float4(acc[4], acc[5], acc[6], acc[7]);
    }
}

// ---------- fp32 fallback (only if ws too small for the bf16 copy) ----------
__global__ void agnn_rnorm_kernel(const float* __restrict__ x,
                                  float* __restrict__ rn, int n) {
    int wave = (blockIdx.x * blockDim.x + threadIdx.x) >> 6;
    int lane = threadIdx.x & 63;
    if (wave >= n) return;
    const float2 v = *reinterpret_cast<const float2*>(x + (size_t)wave * FDIM + lane * 2);
    float s = v.x * v.x + v.y * v.y;
#pragma unroll
    for (int off = 32; off >= 1; off >>= 1)
        s += __shfl_xor(s, off);
    if (lane == 0) rn[wave] = rsqrtf(s + EPSV);
}

__global__ void agnn_main_f32(const float* __restrict__ x,
                              const int* __restrict__ col_id,
                              const float* __restrict__ rn,
                              const float* __restrict__ beta,
                              float* __restrict__ out, int n) {
    int wave = (blockIdx.x * blockDim.x + threadIdx.x) >> 6;
    int lane = threadIdx.x & 63;
    if (wave >= n) return;
    const int node = wave;
    const float b   = beta[0];
    const float rni = rn[node];
    const float2 xi = *reinterpret_cast<const float2*>(x + (size_t)node * FDIM + lane * 2);
    int cidx = col_id[node * DEG + (lane & 15)];
    float2 xj[DEG];
    float  p[DEG];
    float  rnj[DEG];
#pragma unroll
    for (int k = 0; k < DEG; ++k) {
        int cj = __shfl(cidx, k);
        const float2 v = *reinterpret_cast<const float2*>(x + (size_t)cj * FDIM + lane * 2);
        xj[k] = v; rnj[k] = rn[cj];
        p[k] = fmaf(xi.x, v.x, xi.y * v.y);
    }
#pragma unroll
    for (int off = 32; off >= 1; off >>= 1) {
#pragma unroll
        for (int k = 0; k < DEG; ++k)
            p[k] += __shfl_xor(p[k], off);
    }
    const float brni = b * rni;
#pragma unroll
    for (int k = 0; k < DEG; ++k) p[k] *= brni * rnj[k];
    float m = p[0];
#pragma unroll
    for (int k = 1; k < DEG; ++k) m = fmaxf(m, p[k]);
    float s = 0.f;
#pragma unroll
    for (int k = 0; k < DEG; ++k) { p[k] = __expf(p[k] - m); s += p[k]; }
    const float inv = 1.0f / s;
    float2 acc = make_float2(0.f, 0.f);
#pragma unroll
    for (int k = 0; k < DEG; ++k) {
        const float a = p[k] * inv;
        acc.x = fmaf(a, xj[k].x, acc.x);
        acc.y = fmaf(a, xj[k].y, acc.y);
    }
    *reinterpret_cast<float2*>(out + (size_t)node * FDIM + lane * 2) = acc;
}

extern "C" void kernel_launch(void* const* d_in, const int* in_sizes, int n_in,
                              void* d_out, int out_size, void* d_ws, size_t ws_size,
                              hipStream_t stream) {
    const float* x      = (const float*)d_in[0];
    const int*   col_id = (const int*)d_in[3];
    const float* beta   = (const float*)d_in[4];
    float*       out    = (float*)d_out;

    const int n = in_sizes[0] / FDIM;            // 50000

    const int block = 256;                       // 4 waves / block
    const int wavesPerBlock = block / 64;
    const int grid = (n + wavesPerBlock - 1) / wavesPerBlock;

    const size_t xbf_bytes = (size_t)n * (FDIM / 2) * sizeof(uint32_t);  // 12.8 MB
    const size_t need = xbf_bytes + (size_t)n * sizeof(float);

    if (ws_size >= need) {
        uint32_t* xbf = (uint32_t*)d_ws;
        float*    rn  = (float*)((char*)d_ws + xbf_bytes);
        agnn_prep_kernel<<<grid, block, 0, stream>>>(x, xbf, rn, n);
        agnn_main_v4<<<grid, block, 0, stream>>>(xbf, col_id, rn, beta, out, n);
    } else {
        float* rn = (float*)d_ws;
        agnn_rnorm_kernel<<<grid, block, 0, stream>>>(x, rn, n);
        agnn_main_f32<<<grid, block, 0, stream>>>(x, col_id, rn, beta, out, n);
    }
}